// Round 4
// baseline (169.765 us; speedup 1.0000x reference)
//
#include <hip/hip_runtime.h>
#include <math.h>

#define H2 256
#define MAXDEG 128
#define APAD 520   // sA row stride (halves): 1040B rows -> 2-way banks (free)
#define HPAD 264   // hbuf row stride (halves): 528B rows -> 2-way banks (free)

typedef _Float16 f16x8 __attribute__((ext_vector_type(8)));
typedef _Float16 f16x4 __attribute__((ext_vector_type(4)));
typedef float f32x4 __attribute__((ext_vector_type(4)));

// ---------------------------------------------------------------------------
// Fused prep: zero cursor + panel counters; nf fp32 -> catfull[:, 0:256) fp16
// (row stride 512); W1[512][256]->W1t[256][512]; W2[256][256]->W2t[256][256].
__global__ __launch_bounds__(256) void prep(
        const float* __restrict__ nf, const float* __restrict__ W1,
        const float* __restrict__ W2, int* __restrict__ cursor,
        int* __restrict__ pctr, _Float16* __restrict__ catfull,
        _Float16* __restrict__ W1t, _Float16* __restrict__ W2t, int n) {
    int flat = blockIdx.x * 256 + threadIdx.x;
    if (flat < n) cursor[flat] = 0;
    if (flat < 2) pctr[flat] = 0;
    if (flat < 512 * 256) {                    // W1t idx = nn*512 + k
        int nn = flat >> 9, k = flat & 511;
        W1t[flat] = (_Float16)W1[(size_t)k * 256 + nn];
    } else if (flat < 512 * 256 + 256 * 256) { // W2t idx2 = nn*256 + k
        int idx2 = flat - 512 * 256;
        int nn = idx2 >> 8, k = idx2 & 255;
        W2t[idx2] = (_Float16)W2[(size_t)k * 256 + nn];
    }
    int wid  = threadIdx.x >> 6;
    int lane = threadIdx.x & 63;
    int row  = blockIdx.x * 4 + wid;
    if (row < n) {
        float4 v = ((const float4*)nf)[(size_t)row * 64 + lane];
        f16x4 h;
        h.x = (_Float16)v.x; h.y = (_Float16)v.y;
        h.z = (_Float16)v.z; h.w = (_Float16)v.w;
        *(f16x4*)&catfull[(size_t)row * 512 + lane * 4] = h;
    }
}

// ---------------------------------------------------------------------------
__global__ void scatter_edges(const int* __restrict__ esrc, const int* __restrict__ edst,
                              int* __restrict__ cursor, int* __restrict__ bucket, int E) {
    int e = blockIdx.x * 256 + threadIdx.x;
    if (e >= E) return;
    int d = edst[e];
    int s = esrc[e];
    int r = atomicAdd(&cursor[d], 1);
    if (r < MAXDEG) bucket[d * MAXDEG + r] = s;
}

// ---------------------------------------------------------------------------
// XCD-verified panel gather. Round 2 pinned panels via blockIdx%8 (heuristic
// mapping, possibly wrong -> null result proves nothing). Here each block
// reads its ACTUAL XCD via s_getreg(HW_REG_XCC_ID) and serves the matching
// 128-col panel (per-XCD gathered working set 2.56 MB < 4 MB L2). Coverage
// is guaranteed by per-panel chunk counters with work-stealing: own panel
// first, then the other; a wrong hwreg read only degrades locality, never
// correctness. Persistent 1024-thread blocks, chunk = 32 nodes, ~1.2K total
// counter atomics (no same-line storm). Inner loop = round-2 verified
// masked 8-edge/iter gather (numerics identical).
__global__ __launch_bounds__(1024, 4) void gather_xcd(
        const float* __restrict__ nf, const int* __restrict__ cursor,
        const int* __restrict__ bucket, _Float16* catfull,
        int* __restrict__ pctr, int M, int nch) {
    __shared__ int sg;
    int tid = threadIdx.x, lane = tid & 63, wid = tid >> 6;   // 16 waves
    int xcc;
    asm volatile("s_getreg_b32 %0, hwreg(HW_REG_XCC_ID, 0, 32)" : "=s"(xcc));
    int myp = (xcc >> 2) & 1;
    int g2 = lane >> 5;          // edge-slot group 0/1
    int c  = lane & 31;          // column quad within panel

    for (int pass = 0; pass < 2; ++pass) {
        int p = myp ^ pass;
        int pc = p * 128 + c * 4;           // column offset (halves)
        while (true) {
            __syncthreads();
            if (tid == 0) sg = atomicAdd(&pctr[p], 1);
            __syncthreads();
            int ch = sg;
            if (ch >= nch) break;
#pragma unroll
            for (int t = 0; t < 2; ++t) {
                int node = ch * 32 + wid * 2 + t;
                if (node >= M) continue;
                int deg  = cursor[node];
                int degc = deg < MAXDEG ? deg : MAXDEG;
                const int* bk = bucket + (size_t)node * MAXDEG;
                float4 acc[4];
#pragma unroll
                for (int k = 0; k < 4; ++k) acc[k] = make_float4(0.f, 0.f, 0.f, 0.f);
                for (int e = 0; e < degc; e += 8) {
#pragma unroll
                    for (int k = 0; k < 4; ++k) {
                        int idx = e + 2 * k + g2;
                        int ii  = idx < degc ? idx : degc - 1;
                        int s   = bk[ii];
                        f16x4 v = *(const f16x4*)&catfull[(size_t)s * 512 + pc];
                        float m = idx < degc ? 1.0f : 0.0f;
                        acc[k].x += m * (float)v.x;
                        acc[k].y += m * (float)v.y;
                        acc[k].z += m * (float)v.z;
                        acc[k].w += m * (float)v.w;
                    }
                }
                float4 tt;
                tt.x = (acc[0].x + acc[1].x) + (acc[2].x + acc[3].x);
                tt.y = (acc[0].y + acc[1].y) + (acc[2].y + acc[3].y);
                tt.z = (acc[0].z + acc[1].z) + (acc[2].z + acc[3].z);
                tt.w = (acc[0].w + acc[1].w) + (acc[2].w + acc[3].w);
                tt.x += __shfl_xor(tt.x, 32);
                tt.y += __shfl_xor(tt.y, 32);
                tt.z += __shfl_xor(tt.z, 32);
                tt.w += __shfl_xor(tt.w, 32);
                if (g2 == 0) {
                    float4 self = ((const float4*)nf)[(size_t)node * 64 + p * 32 + c];
                    float fd = (float)deg;
                    f16x4 o;
                    o.x = (_Float16)(fd * self.x - tt.x);
                    o.y = (_Float16)(fd * self.y - tt.y);
                    o.z = (_Float16)(fd * self.z - tt.z);
                    o.w = (_Float16)(fd * self.w - tt.w);
                    *(f16x4*)&catfull[(size_t)node * 512 + 256 + pc] = o;
                }
            }
        }
    }
}

// ---------------------------------------------------------------------------
// Pure 2-stage GEMM: out = tanh((catfull @ W1t + b1) @ W2t + b2).
// 512 thr / 8 waves; M-tile 16 (grid 625); wave n-tile 32.
__global__ __launch_bounds__(512, 4) void gemm12(
        const _Float16* __restrict__ catfull,
        const _Float16* __restrict__ W1t, const _Float16* __restrict__ W2t,
        const float* __restrict__ b1, const float* __restrict__ b2,
        float* __restrict__ out, int M) {
    __shared__ _Float16 sA[16 * APAD];     // 16.3 KB
    __shared__ _Float16 hbuf[16 * HPAD];   //  8.3 KB

    int tid = threadIdx.x, lane = tid & 63, wid = tid >> 6;   // wid 0..7
    int m0 = blockIdx.x * 16;
    int wn = wid * 32;
    int fm = lane & 15;
    int q  = lane >> 4;
    int fk = q * 8;

    // ---- stage catfull rows -> sA: 16 rows x 64 b128 groups, 2 passes
    {
        int idx = tid;
#pragma unroll
        for (int p = 0; p < 2; ++p, idx += 512) {
            int row = idx >> 6, g = (idx & 63) * 8;
            int r = m0 + row; if (r >= M) r = M - 1;
            *(uint4*)&sA[row * APAD + g] = *(const uint4*)&catfull[(size_t)r * 512 + g];
        }
    }
    __syncthreads();

    // ---- stage 1: h[16][256] = sA @ W1t + b1 ----
    size_t brow[2];
#pragma unroll
    for (int j = 0; j < 2; ++j) brow[j] = (size_t)(wn + j * 16 + fm) * 512 + fk;

    f16x8 wp[4][2];
#pragma unroll
    for (int s = 0; s < 4; ++s)
#pragma unroll
        for (int j = 0; j < 2; ++j)
            wp[s][j] = *(const f16x8*)&W1t[brow[j] + s * 32];

    f32x4 acc[2] = {};
    f16x8 a_cur = *(const f16x8*)&sA[fm * APAD + fk];
#pragma unroll
    for (int kb = 0; kb < 512; kb += 32) {
        int slot = (kb >> 5) & 3;
        f16x8 a_nxt;
        if (kb + 32 < 512) a_nxt = *(const f16x8*)&sA[fm * APAD + kb + 32 + fk];
        f16x8 w0 = wp[slot][0], w1 = wp[slot][1];
        if (kb + 128 < 512) {
            wp[slot][0] = *(const f16x8*)&W1t[brow[0] + kb + 128];
            wp[slot][1] = *(const f16x8*)&W1t[brow[1] + kb + 128];
        }
        acc[0] = __builtin_amdgcn_mfma_f32_16x16x32_f16(a_cur, w0, acc[0], 0, 0, 0);
        acc[1] = __builtin_amdgcn_mfma_f32_16x16x32_f16(a_cur, w1, acc[1], 0, 0, 0);
        if (kb + 32 < 512) a_cur = a_nxt;
    }

    // epilogue 1: hbuf[row][ncol], row = q*4+r, ncol = wn + j*16 + fm
#pragma unroll
    for (int j = 0; j < 2; ++j) {
        int ncol = wn + j * 16 + fm;
        float bv = b1[ncol];
#pragma unroll
        for (int r = 0; r < 4; ++r)
            hbuf[(q * 4 + r) * HPAD + ncol] = (_Float16)(acc[j][r] + bv);
    }
    __syncthreads();

    // ---- stage 2: out[16][256] = tanh(h @ W2t + b2) ----
    size_t brow2[2];
#pragma unroll
    for (int j = 0; j < 2; ++j) brow2[j] = (size_t)(wn + j * 16 + fm) * 256 + fk;

#pragma unroll
    for (int s = 0; s < 4; ++s)
#pragma unroll
        for (int j = 0; j < 2; ++j)
            wp[s][j] = *(const f16x8*)&W2t[brow2[j] + s * 32];

    f32x4 acc2[2] = {};
    a_cur = *(const f16x8*)&hbuf[fm * HPAD + fk];
#pragma unroll
    for (int kb = 0; kb < 256; kb += 32) {
        int slot = (kb >> 5) & 3;
        f16x8 a_nxt;
        if (kb + 32 < 256) a_nxt = *(const f16x8*)&hbuf[fm * HPAD + kb + 32 + fk];
        f16x8 w0 = wp[slot][0], w1 = wp[slot][1];
        if (kb + 128 < 256) {
            wp[slot][0] = *(const f16x8*)&W2t[brow2[0] + kb + 128];
            wp[slot][1] = *(const f16x8*)&W2t[brow2[1] + kb + 128];
        }
        acc2[0] = __builtin_amdgcn_mfma_f32_16x16x32_f16(a_cur, w0, acc2[0], 0, 0, 0);
        acc2[1] = __builtin_amdgcn_mfma_f32_16x16x32_f16(a_cur, w1, acc2[1], 0, 0, 0);
        if (kb + 32 < 256) a_cur = a_nxt;
    }

    // epilogue 2
#pragma unroll
    for (int j = 0; j < 2; ++j) {
        int ncol = wn + j * 16 + fm;
        float bv = b2[ncol];
#pragma unroll
        for (int r = 0; r < 4; ++r) {
            int row = m0 + q * 4 + r;
            if (row < M) out[(size_t)row * 256 + ncol] = tanhf(acc2[j][r] + bv);
        }
    }
}

// ---------------------------------------------------------------------------
extern "C" void kernel_launch(void* const* d_in, const int* in_sizes, int n_in,
                              void* d_out, int out_size, void* d_ws, size_t ws_size,
                              hipStream_t stream) {
    const float* nf  = (const float*)d_in[0];   // [N, 256] fp32
    const float* W1  = (const float*)d_in[1];   // [512, 256]
    const float* b1  = (const float*)d_in[2];   // [256]
    const float* W2  = (const float*)d_in[3];   // [256, 256]
    const float* b2  = (const float*)d_in[4];   // [256]
    const int* esrc  = (const int*)d_in[5];     // [E]
    const int* edst  = (const int*)d_in[6];     // [E]
    float* out = (float*)d_out;                 // [N, 256] fp32

    int N = in_sizes[0] / H2;
    int E = in_sizes[5];

    char* ws = (char*)d_ws;
    size_t off = 0;
    auto take = [&](size_t bytes) { size_t o = off; off += (bytes + 255) / 256 * 256; return o; };
    int*       cursor  = (int*)(ws + take((size_t)N * 4));
    int*       pctr    = (int*)(ws + take(2 * 4));
    int*       bucket  = (int*)(ws + take((size_t)N * MAXDEG * 4));
    _Float16*  catfull = (_Float16*)(ws + take((size_t)N * 512 * 2));
    _Float16*  W1t     = (_Float16*)(ws + take(512 * 256 * 2));
    _Float16*  W2t     = (_Float16*)(ws + take(256 * 256 * 2));

    prep<<<(N + 3) / 4, 256, 0, stream>>>(nf, W1, W2, cursor, pctr, catfull, W1t, W2t, N);
    scatter_edges<<<(E + 255) / 256, 256, 0, stream>>>(esrc, edst, cursor, bucket, E);

    int nch = (N + 31) / 32;   // 32-node chunks per panel
    gather_xcd<<<512, 1024, 0, stream>>>(nf, cursor, bucket, catfull, pctr, N, nch);

    gemm12<<<(N + 15) / 16, 512, 0, stream>>>(catfull, W1t, W2t, b1, b2, out, N);
}

// Round 5
// 162.566 us; speedup vs baseline: 1.0443x; 1.0443x over previous
//
#include <hip/hip_runtime.h>
#include <math.h>

#define H2 256
#define MAXDEG 128
#define APAD 520   // sA row stride (halves): 1040B rows -> 2-way banks (free)
#define HPAD 264   // hbuf row stride (halves): 528B rows -> 2-way banks (free)
#define NSLICE 32  // 8 fp16 cols per slice
#define NCHUNK 8   // dst-node chunks

typedef _Float16 f16x8 __attribute__((ext_vector_type(8)));
typedef _Float16 f16x4 __attribute__((ext_vector_type(4)));
typedef float f32x4 __attribute__((ext_vector_type(4)));
typedef unsigned short u16x4 __attribute__((ext_vector_type(4)));

// ---------------------------------------------------------------------------
// Fused prep: zero cursor; nf fp32 -> catfull[:, 0:256) fp16 (row stride 512)
// AND slice-major copy catT[slice][node][8] (16B chunks; L2 merges to full
// lines since every byte is written); W1 -> W1t; W2 -> W2t.
__global__ __launch_bounds__(256) void prep(
        const float* __restrict__ nf, const float* __restrict__ W1,
        const float* __restrict__ W2, int* __restrict__ cursor,
        _Float16* __restrict__ catfull, _Float16* __restrict__ catT,
        _Float16* __restrict__ W1t, _Float16* __restrict__ W2t, int n) {
    int flat = blockIdx.x * 256 + threadIdx.x;
    if (flat < n) cursor[flat] = 0;
    if (flat < 512 * 256) {                    // W1t idx = nn*512 + k
        int nn = flat >> 9, k = flat & 511;
        W1t[flat] = (_Float16)W1[(size_t)k * 256 + nn];
    } else if (flat < 512 * 256 + 256 * 256) { // W2t idx2 = nn*256 + k
        int idx2 = flat - 512 * 256;
        int nn = idx2 >> 8, k = idx2 & 255;
        W2t[idx2] = (_Float16)W2[(size_t)k * 256 + nn];
    }
    int wid  = threadIdx.x >> 6;
    int lane = threadIdx.x & 63;
    int row  = blockIdx.x * 4 + wid;
    if (row < n) {
        float4 v = ((const float4*)nf)[(size_t)row * 64 + lane];
        f16x4 h;
        h.x = (_Float16)v.x; h.y = (_Float16)v.y;
        h.z = (_Float16)v.z; h.w = (_Float16)v.w;
        *(f16x4*)&catfull[(size_t)row * 512 + lane * 4] = h;
        // slice-major: cols 4*lane..4*lane+3 -> slice lane>>1, half (lane&1)
        int sl = lane >> 1;
        *(f16x4*)&catT[((size_t)sl * n + row) * 8 + (lane & 1) * 4] = h;
    }
}

// ---------------------------------------------------------------------------
// int16 buckets: N < 32768, so src ids fit ushort. Halves bucket traffic.
__global__ void scatter_edges(const int* __restrict__ esrc, const int* __restrict__ edst,
                              int* __restrict__ cursor, unsigned short* __restrict__ bucket,
                              int E) {
    int e = blockIdx.x * 256 + threadIdx.x;
    if (e >= E) return;
    int d = edst[e];
    int s = esrc[e];
    int r = atomicAdd(&cursor[d], 1);
    if (r < MAXDEG) bucket[(size_t)d * MAXDEG + r] = (unsigned short)s;
}

// ---------------------------------------------------------------------------
// LDS-table gather: an 8-col fp16 slice of the table for ALL N nodes is
// N*16 B (156 KiB) -> fits 160 KiB LDS, so table gathers do ZERO VMEM
// traffic. 32 slices x 8 dst-chunks = 256 blocks (1/CU, full-LDS). Block:
// coalesced table load from catT, one barrier, then lane-per-dst: each lane
// walks its bucket (ushort4 index quads, prefetched) with one ds_read_b128
// per edge + 8 fp32 accumulators. Numerics identical to all prior variants:
// f32 accumulate, f32 deg*self (from nf), single fp16 round on output.
__global__ __launch_bounds__(1024, 1) void gather_lds(
        const float* __restrict__ nf, const int* __restrict__ cursor,
        const unsigned short* __restrict__ bucket, const _Float16* __restrict__ catT,
        _Float16* __restrict__ catfull, int M) {
    extern __shared__ _Float16 tab[];   // M * 8 halves = M*16 B
    int tid = threadIdx.x;
    int s = blockIdx.x & (NSLICE - 1);
    int c = blockIdx.x >> 5;

    for (int i = tid; i < M; i += 1024)
        *(f16x8*)&tab[(size_t)i * 8] = *(const f16x8*)&catT[((size_t)s * M + i) * 8];
    __syncthreads();

    int CH = (M + NCHUNK - 1) / NCHUNK;
    int d0 = c * CH;
    int d1 = d0 + CH < M ? d0 + CH : M;
    for (int d = d0 + tid; d < d1; d += 1024) {
        int deg  = cursor[d];
        int degc = deg < MAXDEG ? deg : MAXDEG;
        const unsigned short* bk = bucket + (size_t)d * MAXDEG;
        float a0 = 0.f, a1 = 0.f, a2 = 0.f, a3 = 0.f;
        float a4 = 0.f, a5 = 0.f, a6 = 0.f, a7 = 0.f;
        if (degc > 0) {
            u16x4 id = *(const u16x4*)&bk[0];
            for (int e = 0; e < degc; e += 4) {
                int en = e + 4; if (en > MAXDEG - 4) en = MAXDEG - 4;
                u16x4 nx = *(const u16x4*)&bk[en];   // prefetch next quad
                {   // e+0 always valid (loop condition)
                    f16x8 v = *(const f16x8*)&tab[(size_t)id.x * 8];
                    a0 += (float)v[0]; a1 += (float)v[1];
                    a2 += (float)v[2]; a3 += (float)v[3];
                    a4 += (float)v[4]; a5 += (float)v[5];
                    a6 += (float)v[6]; a7 += (float)v[7];
                }
                {
                    int ok = (e + 1) < degc;
                    int m  = ok ? (int)id.y : (int)id.x;
                    float w = ok ? 1.f : 0.f;
                    f16x8 v = *(const f16x8*)&tab[(size_t)m * 8];
                    a0 += w * (float)v[0]; a1 += w * (float)v[1];
                    a2 += w * (float)v[2]; a3 += w * (float)v[3];
                    a4 += w * (float)v[4]; a5 += w * (float)v[5];
                    a6 += w * (float)v[6]; a7 += w * (float)v[7];
                }
                {
                    int ok = (e + 2) < degc;
                    int m  = ok ? (int)id.z : (int)id.x;
                    float w = ok ? 1.f : 0.f;
                    f16x8 v = *(const f16x8*)&tab[(size_t)m * 8];
                    a0 += w * (float)v[0]; a1 += w * (float)v[1];
                    a2 += w * (float)v[2]; a3 += w * (float)v[3];
                    a4 += w * (float)v[4]; a5 += w * (float)v[5];
                    a6 += w * (float)v[6]; a7 += w * (float)v[7];
                }
                {
                    int ok = (e + 3) < degc;
                    int m  = ok ? (int)id.w : (int)id.x;
                    float w = ok ? 1.f : 0.f;
                    f16x8 v = *(const f16x8*)&tab[(size_t)m * 8];
                    a0 += w * (float)v[0]; a1 += w * (float)v[1];
                    a2 += w * (float)v[2]; a3 += w * (float)v[3];
                    a4 += w * (float)v[4]; a5 += w * (float)v[5];
                    a6 += w * (float)v[6]; a7 += w * (float)v[7];
                }
                id = nx;
            }
        }
        float fd = (float)deg;
        const float* sp = &nf[(size_t)d * 256 + s * 8];
        float4 s0 = *(const float4*)sp;
        float4 s1 = *(const float4*)(sp + 4);
        f16x8 o;
        o[0] = (_Float16)(fd * s0.x - a0);
        o[1] = (_Float16)(fd * s0.y - a1);
        o[2] = (_Float16)(fd * s0.z - a2);
        o[3] = (_Float16)(fd * s0.w - a3);
        o[4] = (_Float16)(fd * s1.x - a4);
        o[5] = (_Float16)(fd * s1.y - a5);
        o[6] = (_Float16)(fd * s1.z - a6);
        o[7] = (_Float16)(fd * s1.w - a7);
        *(f16x8*)&catfull[(size_t)d * 512 + 256 + s * 8] = o;
    }
}

// ---------------------------------------------------------------------------
// Fallback gather (VMEM path), used only if 160 KiB dynamic LDS unavailable
// or N exceeds LDS table capacity. ushort buckets.
__global__ __launch_bounds__(256) void gather_vmem(
        const float* __restrict__ nf, const int* __restrict__ cursor,
        const unsigned short* __restrict__ bucket, _Float16* __restrict__ catfull, int M) {
    int lane = threadIdx.x & 63, wid = threadIdx.x >> 6;
    int node = blockIdx.x * 4 + wid;
    if (node >= M) return;
    int deg = cursor[node];
    int degc = deg < MAXDEG ? deg : MAXDEG;
    const unsigned short* bk = bucket + (size_t)node * MAXDEG;
    float4 accA = make_float4(0.f, 0.f, 0.f, 0.f);
    float4 accB = make_float4(0.f, 0.f, 0.f, 0.f);
    int e = 0;
    for (; e + 8 <= degc; e += 8) {
        u16x4 sa = *(const u16x4*)&bk[e];
        u16x4 sb = *(const u16x4*)&bk[e + 4];
        f16x4 v0 = *(const f16x4*)&catfull[(size_t)sa.x * 512 + lane * 4];
        f16x4 v1 = *(const f16x4*)&catfull[(size_t)sa.y * 512 + lane * 4];
        f16x4 v2 = *(const f16x4*)&catfull[(size_t)sa.z * 512 + lane * 4];
        f16x4 v3 = *(const f16x4*)&catfull[(size_t)sa.w * 512 + lane * 4];
        f16x4 v4 = *(const f16x4*)&catfull[(size_t)sb.x * 512 + lane * 4];
        f16x4 v5 = *(const f16x4*)&catfull[(size_t)sb.y * 512 + lane * 4];
        f16x4 v6 = *(const f16x4*)&catfull[(size_t)sb.z * 512 + lane * 4];
        f16x4 v7 = *(const f16x4*)&catfull[(size_t)sb.w * 512 + lane * 4];
        accA.x += ((float)v0.x + (float)v1.x) + ((float)v2.x + (float)v3.x);
        accA.y += ((float)v0.y + (float)v1.y) + ((float)v2.y + (float)v3.y);
        accA.z += ((float)v0.z + (float)v1.z) + ((float)v2.z + (float)v3.z);
        accA.w += ((float)v0.w + (float)v1.w) + ((float)v2.w + (float)v3.w);
        accB.x += ((float)v4.x + (float)v5.x) + ((float)v6.x + (float)v7.x);
        accB.y += ((float)v4.y + (float)v5.y) + ((float)v6.y + (float)v7.y);
        accB.z += ((float)v4.z + (float)v5.z) + ((float)v6.z + (float)v7.z);
        accB.w += ((float)v4.w + (float)v5.w) + ((float)v6.w + (float)v7.w);
    }
    for (; e < degc; ++e) {
        int s = bk[e];
        f16x4 v = *(const f16x4*)&catfull[(size_t)s * 512 + lane * 4];
        accA.x += (float)v.x; accA.y += (float)v.y;
        accA.z += (float)v.z; accA.w += (float)v.w;
    }
    float4 self = ((const float4*)nf)[(size_t)node * 64 + lane];
    float fd = (float)deg;
    f16x4 o;
    o.x = (_Float16)(fd * self.x - (accA.x + accB.x));
    o.y = (_Float16)(fd * self.y - (accA.y + accB.y));
    o.z = (_Float16)(fd * self.z - (accA.z + accB.z));
    o.w = (_Float16)(fd * self.w - (accA.w + accB.w));
    *(f16x4*)&catfull[(size_t)node * 512 + 256 + lane * 4] = o;
}

// ---------------------------------------------------------------------------
// Enable >64 KiB dynamic LDS at .so load time — OUTSIDE kernel_launch and
// outside any graph capture (R3 set it inside kernel_launch; if that call
// failed under capture, the LDS path silently never ran).
static int g_biglds = 0;
struct BigLdsInit {
    BigLdsInit() {
        g_biglds = (hipFuncSetAttribute((const void*)gather_lds,
                        hipFuncAttributeMaxDynamicSharedMemorySize,
                        160 * 1024) == hipSuccess) ? 1 : 0;
    }
};
static BigLdsInit g_biglds_init;

// ---------------------------------------------------------------------------
// Pure 2-stage GEMM: out = tanh((catfull @ W1t + b1) @ W2t + b2).
// 512 thr / 8 waves; M-tile 16 (grid 625); wave n-tile 32.
__global__ __launch_bounds__(512, 4) void gemm12(
        const _Float16* __restrict__ catfull,
        const _Float16* __restrict__ W1t, const _Float16* __restrict__ W2t,
        const float* __restrict__ b1, const float* __restrict__ b2,
        float* __restrict__ out, int M) {
    __shared__ _Float16 sA[16 * APAD];     // 16.3 KB
    __shared__ _Float16 hbuf[16 * HPAD];   //  8.3 KB

    int tid = threadIdx.x, lane = tid & 63, wid = tid >> 6;   // wid 0..7
    int m0 = blockIdx.x * 16;
    int wn = wid * 32;
    int fm = lane & 15;
    int q  = lane >> 4;
    int fk = q * 8;

    // ---- stage catfull rows -> sA: 16 rows x 64 b128 groups, 2 passes
    {
        int idx = tid;
#pragma unroll
        for (int p = 0; p < 2; ++p, idx += 512) {
            int row = idx >> 6, g = (idx & 63) * 8;
            int r = m0 + row; if (r >= M) r = M - 1;
            *(uint4*)&sA[row * APAD + g] = *(const uint4*)&catfull[(size_t)r * 512 + g];
        }
    }
    __syncthreads();

    // ---- stage 1: h[16][256] = sA @ W1t + b1 ----
    size_t brow[2];
#pragma unroll
    for (int j = 0; j < 2; ++j) brow[j] = (size_t)(wn + j * 16 + fm) * 512 + fk;

    f16x8 wp[4][2];
#pragma unroll
    for (int s = 0; s < 4; ++s)
#pragma unroll
        for (int j = 0; j < 2; ++j)
            wp[s][j] = *(const f16x8*)&W1t[brow[j] + s * 32];

    f32x4 acc[2] = {};
    f16x8 a_cur = *(const f16x8*)&sA[fm * APAD + fk];
#pragma unroll
    for (int kb = 0; kb < 512; kb += 32) {
        int slot = (kb >> 5) & 3;
        f16x8 a_nxt;
        if (kb + 32 < 512) a_nxt = *(const f16x8*)&sA[fm * APAD + kb + 32 + fk];
        f16x8 w0 = wp[slot][0], w1 = wp[slot][1];
        if (kb + 128 < 512) {
            wp[slot][0] = *(const f16x8*)&W1t[brow[0] + kb + 128];
            wp[slot][1] = *(const f16x8*)&W1t[brow[1] + kb + 128];
        }
        acc[0] = __builtin_amdgcn_mfma_f32_16x16x32_f16(a_cur, w0, acc[0], 0, 0, 0);
        acc[1] = __builtin_amdgcn_mfma_f32_16x16x32_f16(a_cur, w1, acc[1], 0, 0, 0);
        if (kb + 32 < 512) a_cur = a_nxt;
    }

    // epilogue 1: hbuf[row][ncol], row = q*4+r, ncol = wn + j*16 + fm
#pragma unroll
    for (int j = 0; j < 2; ++j) {
        int ncol = wn + j * 16 + fm;
        float bv = b1[ncol];
#pragma unroll
        for (int r = 0; r < 4; ++r)
            hbuf[(q * 4 + r) * HPAD + ncol] = (_Float16)(acc[j][r] + bv);
    }
    __syncthreads();

    // ---- stage 2: out[16][256] = tanh(h @ W2t + b2) ----
    size_t brow2[2];
#pragma unroll
    for (int j = 0; j < 2; ++j) brow2[j] = (size_t)(wn + j * 16 + fm) * 256 + fk;

#pragma unroll
    for (int s = 0; s < 4; ++s)
#pragma unroll
        for (int j = 0; j < 2; ++j)
            wp[s][j] = *(const f16x8*)&W2t[brow2[j] + s * 32];

    f32x4 acc2[2] = {};
    a_cur = *(const f16x8*)&hbuf[fm * HPAD + fk];
#pragma unroll
    for (int kb = 0; kb < 256; kb += 32) {
        int slot = (kb >> 5) & 3;
        f16x8 a_nxt;
        if (kb + 32 < 256) a_nxt = *(const f16x8*)&hbuf[fm * HPAD + kb + 32 + fk];
        f16x8 w0 = wp[slot][0], w1 = wp[slot][1];
        if (kb + 128 < 256) {
            wp[slot][0] = *(const f16x8*)&W2t[brow2[0] + kb + 128];
            wp[slot][1] = *(const f16x8*)&W2t[brow2[1] + kb + 128];
        }
        acc2[0] = __builtin_amdgcn_mfma_f32_16x16x32_f16(a_cur, w0, acc2[0], 0, 0, 0);
        acc2[1] = __builtin_amdgcn_mfma_f32_16x16x32_f16(a_cur, w1, acc2[1], 0, 0, 0);
        if (kb + 32 < 256) a_cur = a_nxt;
    }

    // epilogue 2
#pragma unroll
    for (int j = 0; j < 2; ++j) {
        int ncol = wn + j * 16 + fm;
        float bv = b2[ncol];
#pragma unroll
        for (int r = 0; r < 4; ++r) {
            int row = m0 + q * 4 + r;
            if (row < M) out[(size_t)row * 256 + ncol] = tanhf(acc2[j][r] + bv);
        }
    }
}

// ---------------------------------------------------------------------------
extern "C" void kernel_launch(void* const* d_in, const int* in_sizes, int n_in,
                              void* d_out, int out_size, void* d_ws, size_t ws_size,
                              hipStream_t stream) {
    const float* nf  = (const float*)d_in[0];   // [N, 256] fp32
    const float* W1  = (const float*)d_in[1];   // [512, 256]
    const float* b1  = (const float*)d_in[2];   // [256]
    const float* W2  = (const float*)d_in[3];   // [256, 256]
    const float* b2  = (const float*)d_in[4];   // [256]
    const int* esrc  = (const int*)d_in[5];     // [E]
    const int* edst  = (const int*)d_in[6];     // [E]
    float* out = (float*)d_out;                 // [N, 256] fp32

    int N = in_sizes[0] / H2;
    int E = in_sizes[5];

    char* ws = (char*)d_ws;
    size_t off = 0;
    auto take = [&](size_t bytes) { size_t o = off; off += (bytes + 255) / 256 * 256; return o; };
    int*            cursor  = (int*)(ws + take((size_t)N * 4));
    unsigned short* bucket  = (unsigned short*)(ws + take((size_t)N * MAXDEG * 2));
    _Float16*       catfull = (_Float16*)(ws + take((size_t)N * 512 * 2));
    _Float16*       catT    = (_Float16*)(ws + take((size_t)NSLICE * N * 8 * 2));
    _Float16*       W1t     = (_Float16*)(ws + take(512 * 256 * 2));
    _Float16*       W2t     = (_Float16*)(ws + take(256 * 256 * 2));

    // Retry attribute once if the load-time ctor failed (R3 showed the call
    // itself is harmless inside kernel_launch).
    if (!g_biglds) {
        static int tried = 0;
        if (!tried) {
            tried = 1;
            g_biglds = (hipFuncSetAttribute((const void*)gather_lds,
                            hipFuncAttributeMaxDynamicSharedMemorySize,
                            160 * 1024) == hipSuccess) ? 1 : 0;
        }
    }
    size_t tab_bytes = (size_t)N * 8 * sizeof(_Float16);   // N*16 B

    prep<<<(N + 3) / 4, 256, 0, stream>>>(nf, W1, W2, cursor, catfull, catT, W1t, W2t, N);
    scatter_edges<<<(E + 255) / 256, 256, 0, stream>>>(esrc, edst, cursor, bucket, E);

    if (g_biglds && tab_bytes <= 160u * 1024u && N < 32768) {
        gather_lds<<<NSLICE * NCHUNK, 1024, tab_bytes, stream>>>(
            nf, cursor, bucket, catT, catfull, N);
    } else {
        gather_vmem<<<(N + 3) / 4, 256, 0, stream>>>(nf, cursor, bucket, catfull, N);
    }

    gemm12<<<(N + 15) / 16, 512, 0, stream>>>(catfull, W1t, W2t, b1, b2, out, N);
}

// Round 7
// 161.211 us; speedup vs baseline: 1.0531x; 1.0084x over previous
//
#include <hip/hip_runtime.h>
#include <math.h>

#define H2 256
#define MAXDEG 128
#define APAD 520   // sA row stride (halves): 1040B rows -> 2-way banks (free)
#define HPAD 264   // hbuf row stride (halves): 528B rows -> 2-way banks (free)
#define NSLICE 32  // 8 fp16 cols per slice
#define NCHUNK 8   // dst-node chunks

typedef _Float16 f16x8 __attribute__((ext_vector_type(8)));
typedef _Float16 f16x4 __attribute__((ext_vector_type(4)));
typedef float f32x4 __attribute__((ext_vector_type(4)));
typedef unsigned short u16x4 __attribute__((ext_vector_type(4)));

// ---------------------------------------------------------------------------
// Fused prep: zero cursor; sentinel-fill buckets (index n -> zero table row,
// removes ALL tail masking from the gather); nf fp32 -> catfull[:,0:256) fp16
// (row stride 512) AND slice-major catT[slice][node][8]; W1->W1t; W2->W2t.
__global__ __launch_bounds__(256) void prep(
        const float* __restrict__ nf, const float* __restrict__ W1,
        const float* __restrict__ W2, int* __restrict__ cursor,
        unsigned short* __restrict__ bucket,
        _Float16* __restrict__ catfull, _Float16* __restrict__ catT,
        _Float16* __restrict__ W1t, _Float16* __restrict__ W2t, int n) {
    int flat = blockIdx.x * 256 + threadIdx.x;
    if (flat < n) cursor[flat] = 0;
    if (flat < n * (MAXDEG / 4)) {             // sentinel-fill buckets, u16x4
        unsigned short sv = (unsigned short)n;
        u16x4 s4; s4.x = sv; s4.y = sv; s4.z = sv; s4.w = sv;
        *(u16x4*)&bucket[(size_t)flat * 4] = s4;
    }
    if (flat < 512 * 256) {                    // W1t idx = nn*512 + k
        int nn = flat >> 9, k = flat & 511;
        W1t[flat] = (_Float16)W1[(size_t)k * 256 + nn];
    } else if (flat < 512 * 256 + 256 * 256) { // W2t idx2 = nn*256 + k
        int idx2 = flat - 512 * 256;
        int nn = idx2 >> 8, k = idx2 & 255;
        W2t[idx2] = (_Float16)W2[(size_t)k * 256 + nn];
    }
    int wid  = threadIdx.x >> 6;
    int lane = threadIdx.x & 63;
    int row  = blockIdx.x * 4 + wid;
    if (row < n) {
        float4 v = ((const float4*)nf)[(size_t)row * 64 + lane];
        f16x4 h;
        h.x = (_Float16)v.x; h.y = (_Float16)v.y;
        h.z = (_Float16)v.z; h.w = (_Float16)v.w;
        *(f16x4*)&catfull[(size_t)row * 512 + lane * 4] = h;
        // slice-major: cols 4*lane..4*lane+3 -> slice lane>>1, half (lane&1)
        int sl = lane >> 1;
        *(f16x4*)&catT[((size_t)sl * n + row) * 8 + (lane & 1) * 4] = h;
    }
}

// ---------------------------------------------------------------------------
__global__ void scatter_edges(const int* __restrict__ esrc, const int* __restrict__ edst,
                              int* __restrict__ cursor, unsigned short* __restrict__ bucket,
                              int E) {
    int e = blockIdx.x * 256 + threadIdx.x;
    if (e >= E) return;
    int d = edst[e];
    int s = esrc[e];
    int r = atomicAdd(&cursor[d], 1);
    if (r < MAXDEG) bucket[(size_t)d * MAXDEG + r] = (unsigned short)s;
}

// ---------------------------------------------------------------------------
// LDS-table gather: an 8-col fp16 slice of the table for ALL N nodes plus a
// zero sentinel row is (N+1)*16 B (156.3 KiB @ N=10000) -> fits 160 KiB LDS,
// so table gathers do ZERO VMEM traffic (the ~40 us random-line floor of all
// VMEM variants disappears). 32 slices x 8 dst-chunks = 256 blocks (1/CU).
// Sentinel-padded buckets -> branch-free inner loop: per 4 edges, one u16x4
// index read + 4x {ds_read_b128 + 8 mixed fma}. fp32 accumulate, order
// ascending-e identical to all prior variants (sentinel terms add exact 0).
__global__ __launch_bounds__(1024, 1) void gather_lds(
        const float* __restrict__ nf, const int* __restrict__ cursor,
        const unsigned short* __restrict__ bucket, const _Float16* __restrict__ catT,
        _Float16* __restrict__ catfull, int M) {
    extern __shared__ _Float16 tab[];   // (M+1) * 8 halves
    int tid = threadIdx.x;
    int s = blockIdx.x & (NSLICE - 1);
    int c = blockIdx.x >> 5;

    for (int i = tid; i < M; i += 1024)
        *(f16x8*)&tab[(size_t)i * 8] = *(const f16x8*)&catT[((size_t)s * M + i) * 8];
    if (tid < 8) tab[(size_t)M * 8 + tid] = (_Float16)0;   // sentinel row
    __syncthreads();

    int CH = (M + NCHUNK - 1) / NCHUNK;
    int d0 = c * CH;
    int d1 = d0 + CH < M ? d0 + CH : M;
    for (int d = d0 + tid; d < d1; d += 1024) {
        int deg  = cursor[d];
        int degc = deg < MAXDEG ? deg : MAXDEG;
        int degp = (degc + 3) & ~3;            // sentinel-padded, mult of 4
        const unsigned short* bk = bucket + (size_t)d * MAXDEG;
        float a0 = 0.f, a1 = 0.f, a2 = 0.f, a3 = 0.f;
        float a4 = 0.f, a5 = 0.f, a6 = 0.f, a7 = 0.f;
        u16x4 id = *(const u16x4*)&bk[0];
        for (int e = 0; e < degp; e += 4) {
            int en = e + 4; if (en > MAXDEG - 4) en = MAXDEG - 4;
            u16x4 nx = *(const u16x4*)&bk[en];   // prefetch next quad
            {
                f16x8 v = *(const f16x8*)&tab[(size_t)id.x * 8];
                a0 += (float)v[0]; a1 += (float)v[1];
                a2 += (float)v[2]; a3 += (float)v[3];
                a4 += (float)v[4]; a5 += (float)v[5];
                a6 += (float)v[6]; a7 += (float)v[7];
            }
            {
                f16x8 v = *(const f16x8*)&tab[(size_t)id.y * 8];
                a0 += (float)v[0]; a1 += (float)v[1];
                a2 += (float)v[2]; a3 += (float)v[3];
                a4 += (float)v[4]; a5 += (float)v[5];
                a6 += (float)v[6]; a7 += (float)v[7];
            }
            {
                f16x8 v = *(const f16x8*)&tab[(size_t)id.z * 8];
                a0 += (float)v[0]; a1 += (float)v[1];
                a2 += (float)v[2]; a3 += (float)v[3];
                a4 += (float)v[4]; a5 += (float)v[5];
                a6 += (float)v[6]; a7 += (float)v[7];
            }
            {
                f16x8 v = *(const f16x8*)&tab[(size_t)id.w * 8];
                a0 += (float)v[0]; a1 += (float)v[1];
                a2 += (float)v[2]; a3 += (float)v[3];
                a4 += (float)v[4]; a5 += (float)v[5];
                a6 += (float)v[6]; a7 += (float)v[7];
            }
            id = nx;
        }
        float fd = (float)deg;
        const float* sp = &nf[(size_t)d * 256 + s * 8];
        float4 s0 = *(const float4*)sp;
        float4 s1 = *(const float4*)(sp + 4);
        f16x8 o;
        o[0] = (_Float16)(fd * s0.x - a0);
        o[1] = (_Float16)(fd * s0.y - a1);
        o[2] = (_Float16)(fd * s0.z - a2);
        o[3] = (_Float16)(fd * s0.w - a3);
        o[4] = (_Float16)(fd * s1.x - a4);
        o[5] = (_Float16)(fd * s1.y - a5);
        o[6] = (_Float16)(fd * s1.z - a6);
        o[7] = (_Float16)(fd * s1.w - a7);
        *(f16x8*)&catfull[(size_t)d * 512 + 256 + s * 8] = o;
    }
}

// ---------------------------------------------------------------------------
// Fallback gather (VMEM path) — only if big-LDS attribute unavailable.
__global__ __launch_bounds__(256) void gather_vmem(
        const float* __restrict__ nf, const int* __restrict__ cursor,
        const unsigned short* __restrict__ bucket, _Float16* __restrict__ catfull, int M) {
    int lane = threadIdx.x & 63, wid = threadIdx.x >> 6;
    int node = blockIdx.x * 4 + wid;
    if (node >= M) return;
    int deg = cursor[node];
    int degc = deg < MAXDEG ? deg : MAXDEG;
    int degp = (degc + 3) & ~3;
    const unsigned short* bk = bucket + (size_t)node * MAXDEG;
    // sentinel rows don't exist in catfull; clamp sentinel to 0 with weight 0
    float4 accA = make_float4(0.f, 0.f, 0.f, 0.f);
    for (int e = 0; e < degp; ++e) {
        int s = bk[e];
        int ok = e < degc;
        int si = ok ? s : 0;
        float w = ok ? 1.f : 0.f;
        f16x4 v = *(const f16x4*)&catfull[(size_t)si * 512 + lane * 4];
        accA.x += w * (float)v.x; accA.y += w * (float)v.y;
        accA.z += w * (float)v.z; accA.w += w * (float)v.w;
    }
    float4 self = ((const float4*)nf)[(size_t)node * 64 + lane];
    float fd = (float)deg;
    f16x4 o;
    o.x = (_Float16)(fd * self.x - accA.x);
    o.y = (_Float16)(fd * self.y - accA.y);
    o.z = (_Float16)(fd * self.z - accA.z);
    o.w = (_Float16)(fd * self.w - accA.w);
    *(f16x4*)&catfull[(size_t)node * 512 + 256 + lane * 4] = o;
}

// Marker: makes the fallback path 5 dispatches (fill ord spacing 14 vs 13),
// so the executed path is identifiable from the profile.
__global__ void marker_k() {}

// ---------------------------------------------------------------------------
// Pure 2-stage GEMM: out = tanh((catfull @ W1t + b1) @ W2t + b2).
__global__ __launch_bounds__(512, 4) void gemm12(
        const _Float16* __restrict__ catfull,
        const _Float16* __restrict__ W1t, const _Float16* __restrict__ W2t,
        const float* __restrict__ b1, const float* __restrict__ b2,
        float* __restrict__ out, int M) {
    __shared__ _Float16 sA[16 * APAD];     // 16.3 KB
    __shared__ _Float16 hbuf[16 * HPAD];   //  8.3 KB

    int tid = threadIdx.x, lane = tid & 63, wid = tid >> 6;   // wid 0..7
    int m0 = blockIdx.x * 16;
    int wn = wid * 32;
    int fm = lane & 15;
    int q  = lane >> 4;
    int fk = q * 8;

    {
        int idx = tid;
#pragma unroll
        for (int p = 0; p < 2; ++p, idx += 512) {
            int row = idx >> 6, g = (idx & 63) * 8;
            int r = m0 + row; if (r >= M) r = M - 1;
            *(uint4*)&sA[row * APAD + g] = *(const uint4*)&catfull[(size_t)r * 512 + g];
        }
    }
    __syncthreads();

    size_t brow[2];
#pragma unroll
    for (int j = 0; j < 2; ++j) brow[j] = (size_t)(wn + j * 16 + fm) * 512 + fk;

    f16x8 wp[4][2];
#pragma unroll
    for (int s = 0; s < 4; ++s)
#pragma unroll
        for (int j = 0; j < 2; ++j)
            wp[s][j] = *(const f16x8*)&W1t[brow[j] + s * 32];

    f32x4 acc[2] = {};
    f16x8 a_cur = *(const f16x8*)&sA[fm * APAD + fk];
#pragma unroll
    for (int kb = 0; kb < 512; kb += 32) {
        int slot = (kb >> 5) & 3;
        f16x8 a_nxt;
        if (kb + 32 < 512) a_nxt = *(const f16x8*)&sA[fm * APAD + kb + 32 + fk];
        f16x8 w0 = wp[slot][0], w1 = wp[slot][1];
        if (kb + 128 < 512) {
            wp[slot][0] = *(const f16x8*)&W1t[brow[0] + kb + 128];
            wp[slot][1] = *(const f16x8*)&W1t[brow[1] + kb + 128];
        }
        acc[0] = __builtin_amdgcn_mfma_f32_16x16x32_f16(a_cur, w0, acc[0], 0, 0, 0);
        acc[1] = __builtin_amdgcn_mfma_f32_16x16x32_f16(a_cur, w1, acc[1], 0, 0, 0);
        if (kb + 32 < 512) a_cur = a_nxt;
    }

#pragma unroll
    for (int j = 0; j < 2; ++j) {
        int ncol = wn + j * 16 + fm;
        float bv = b1[ncol];
#pragma unroll
        for (int r = 0; r < 4; ++r)
            hbuf[(q * 4 + r) * HPAD + ncol] = (_Float16)(acc[j][r] + bv);
    }
    __syncthreads();

    size_t brow2[2];
#pragma unroll
    for (int j = 0; j < 2; ++j) brow2[j] = (size_t)(wn + j * 16 + fm) * 256 + fk;

#pragma unroll
    for (int s = 0; s < 4; ++s)
#pragma unroll
        for (int j = 0; j < 2; ++j)
            wp[s][j] = *(const f16x8*)&W2t[brow2[j] + s * 32];

    f32x4 acc2[2] = {};
    a_cur = *(const f16x8*)&hbuf[fm * HPAD + fk];
#pragma unroll
    for (int kb = 0; kb < 256; kb += 32) {
        int slot = (kb >> 5) & 3;
        f16x8 a_nxt;
        if (kb + 32 < 256) a_nxt = *(const f16x8*)&hbuf[fm * HPAD + kb + 32 + fk];
        f16x8 w0 = wp[slot][0], w1 = wp[slot][1];
        if (kb + 128 < 256) {
            wp[slot][0] = *(const f16x8*)&W2t[brow2[0] + kb + 128];
            wp[slot][1] = *(const f16x8*)&W2t[brow2[1] + kb + 128];
        }
        acc2[0] = __builtin_amdgcn_mfma_f32_16x16x32_f16(a_cur, w0, acc2[0], 0, 0, 0);
        acc2[1] = __builtin_amdgcn_mfma_f32_16x16x32_f16(a_cur, w1, acc2[1], 0, 0, 0);
        if (kb + 32 < 256) a_cur = a_nxt;
    }

#pragma unroll
    for (int j = 0; j < 2; ++j) {
        int ncol = wn + j * 16 + fm;
        float bv = b2[ncol];
#pragma unroll
        for (int r = 0; r < 4; ++r) {
            int row = m0 + q * 4 + r;
            if (row < M) out[(size_t)row * 256 + ncol] = tanhf(acc2[j][r] + bv);
        }
    }
}

// ---------------------------------------------------------------------------
extern "C" void kernel_launch(void* const* d_in, const int* in_sizes, int n_in,
                              void* d_out, int out_size, void* d_ws, size_t ws_size,
                              hipStream_t stream) {
    const float* nf  = (const float*)d_in[0];   // [N, 256] fp32
    const float* W1  = (const float*)d_in[1];   // [512, 256]
    const float* b1  = (const float*)d_in[2];   // [256]
    const float* W2  = (const float*)d_in[3];   // [256, 256]
    const float* b2  = (const float*)d_in[4];   // [256]
    const int* esrc  = (const int*)d_in[5];     // [E]
    const int* edst  = (const int*)d_in[6];     // [E]
    float* out = (float*)d_out;                 // [N, 256] fp32

    int N = in_sizes[0] / H2;
    int E = in_sizes[5];

    char* ws = (char*)d_ws;
    size_t off = 0;
    auto take = [&](size_t bytes) { size_t o = off; off += (bytes + 255) / 256 * 256; return o; };
    int*            cursor  = (int*)(ws + take((size_t)N * 4));
    unsigned short* bucket  = (unsigned short*)(ws + take((size_t)N * MAXDEG * 2));
    _Float16*       catfull = (_Float16*)(ws + take((size_t)N * 512 * 2));
    _Float16*       catT    = (_Float16*)(ws + take((size_t)NSLICE * N * 8 * 2));
    _Float16*       W1t     = (_Float16*)(ws + take(512 * 256 * 2));
    _Float16*       W2t     = (_Float16*)(ws + take(256 * 256 * 2));

    // Lazy big-LDS opt-in: runtime is initialized here; attribute set is not
    // a stream op (capture-safe — R3 demonstrated the call is harmless).
    static int biglds = -1;
    if (biglds == -1) {
        biglds = (hipFuncSetAttribute((const void*)gather_lds,
                      hipFuncAttributeMaxDynamicSharedMemorySize,
                      160 * 1024) == hipSuccess) ? 1 : 0;
    }
    size_t tab_bytes = ((size_t)N + 1) * 8 * sizeof(_Float16);   // (N+1)*16 B

    prep<<<(N + 3) / 4, 256, 0, stream>>>(nf, W1, W2, cursor, bucket,
                                          catfull, catT, W1t, W2t, N);
    scatter_edges<<<(E + 255) / 256, 256, 0, stream>>>(esrc, edst, cursor, bucket, E);

    if (biglds == 1 && tab_bytes <= 160u * 1024u) {
        gather_lds<<<NSLICE * NCHUNK, 1024, tab_bytes, stream>>>(
            nf, cursor, bucket, catT, catfull, N);
    } else {
        marker_k<<<1, 64, 0, stream>>>();   // path marker: 14-dispatch spacing
        gather_vmem<<<(N + 3) / 4, 256, 0, stream>>>(nf, cursor, bucket, catfull, N);
    }

    gemm12<<<(N + 15) / 16, 512, 0, stream>>>(catfull, W1t, W2t, b1, b2, out, N);
}

// Round 8
// 154.889 us; speedup vs baseline: 1.0960x; 1.0408x over previous
//
#include <hip/hip_runtime.h>
#include <math.h>

#define H2 256
#define MAXDEG 128
#define APAD 520   // sA row stride (halves): 1040B rows -> 2-way banks (free)
#define HPAD 264   // hbuf row stride (halves): 528B rows -> 2-way banks (free)

typedef _Float16 f16x8 __attribute__((ext_vector_type(8)));
typedef _Float16 f16x4 __attribute__((ext_vector_type(4)));
typedef float f32x4 __attribute__((ext_vector_type(4)));
typedef unsigned short u16x4 __attribute__((ext_vector_type(4)));

// ---------------------------------------------------------------------------
// Fused prep (R1-minimal): zero cursor; nf fp32 -> catfull[:, 0:256) fp16
// (row stride 512); W1[512][256]->W1t[256][512]; W2[256][256]->W2t[256][256].
__global__ __launch_bounds__(256) void prep(
        const float* __restrict__ nf, const float* __restrict__ W1,
        const float* __restrict__ W2, int* __restrict__ cursor,
        _Float16* __restrict__ catfull, _Float16* __restrict__ W1t,
        _Float16* __restrict__ W2t, int n) {
    int flat = blockIdx.x * 256 + threadIdx.x;
    if (flat < n) cursor[flat] = 0;
    if (flat < 512 * 256) {                    // W1t idx = nn*512 + k
        int nn = flat >> 9, k = flat & 511;
        W1t[flat] = (_Float16)W1[(size_t)k * 256 + nn];
    } else if (flat < 512 * 256 + 256 * 256) { // W2t idx2 = nn*256 + k
        int idx2 = flat - 512 * 256;
        int nn = idx2 >> 8, k = idx2 & 255;
        W2t[idx2] = (_Float16)W2[(size_t)k * 256 + nn];
    }
    int wid  = threadIdx.x >> 6;
    int lane = threadIdx.x & 63;
    int row  = blockIdx.x * 4 + wid;
    if (row < n) {
        float4 v = ((const float4*)nf)[(size_t)row * 64 + lane];
        f16x4 h;
        h.x = (_Float16)v.x; h.y = (_Float16)v.y;
        h.z = (_Float16)v.z; h.w = (_Float16)v.w;
        *(f16x4*)&catfull[(size_t)row * 512 + lane * 4] = h;
    }
}

// ---------------------------------------------------------------------------
__global__ void scatter_edges(const int* __restrict__ esrc, const int* __restrict__ edst,
                              int* __restrict__ cursor, unsigned short* __restrict__ bucket,
                              int E) {
    int e = blockIdx.x * 256 + threadIdx.x;
    if (e >= E) return;
    int d = edst[e];
    int s = esrc[e];
    int r = atomicAdd(&cursor[d], 1);
    if (r < MAXDEG) bucket[(size_t)d * MAXDEG + r] = (unsigned short)s;
}

// ---------------------------------------------------------------------------
// MLP-deep gather. R0's direct measurement showed VGPR_Count=32 on the fused
// kernel: the 8-wide load group could NOT be held in registers -> the
// compiler serialized gather loads into load->wait->add chains (~500 cy
// each), which reproduces the measured 59.4 us. Fix: standalone gather with
// __launch_bounds__(256,2) (VGPR cap 128 -> ~70 used -> still 4 waves/SIMD)
// and an inner loop holding SIXTEEN row-loads in flight per iteration
// (4 index quads -> 16 f16x4 loads -> pairwise accumulate tree). One node
// per wave; 64 lanes x f16x4 = one coalesced 512B row per load instr.
// Numerics: fp32 accumulate, fp32 deg*self from nf, one fp16 round on
// output — same as all passing variants.
__global__ __launch_bounds__(256, 2) void gather(
        const float* __restrict__ nf, const int* __restrict__ cursor,
        const unsigned short* __restrict__ bucket, _Float16* __restrict__ catfull,
        int M) {
    int lane = threadIdx.x & 63;
    int node = (blockIdx.x * 256 + threadIdx.x) >> 6;
    if (node >= M) return;
    int deg = cursor[node];
    int degc = deg < MAXDEG ? deg : MAXDEG;
    const unsigned short* bk = bucket + (size_t)node * MAXDEG;

    float4 acc0 = make_float4(0.f, 0.f, 0.f, 0.f);
    float4 acc1 = make_float4(0.f, 0.f, 0.f, 0.f);
    float4 acc2 = make_float4(0.f, 0.f, 0.f, 0.f);
    float4 acc3 = make_float4(0.f, 0.f, 0.f, 0.f);

    int e = 0;
    // ---- 16 loads in flight per iteration
    for (; e + 16 <= degc; e += 16) {
        u16x4 i0 = *(const u16x4*)&bk[e];
        u16x4 i1 = *(const u16x4*)&bk[e + 4];
        u16x4 i2 = *(const u16x4*)&bk[e + 8];
        u16x4 i3 = *(const u16x4*)&bk[e + 12];
        f16x4 v0  = *(const f16x4*)&catfull[(size_t)i0.x * 512 + lane * 4];
        f16x4 v1  = *(const f16x4*)&catfull[(size_t)i0.y * 512 + lane * 4];
        f16x4 v2  = *(const f16x4*)&catfull[(size_t)i0.z * 512 + lane * 4];
        f16x4 v3  = *(const f16x4*)&catfull[(size_t)i0.w * 512 + lane * 4];
        f16x4 v4  = *(const f16x4*)&catfull[(size_t)i1.x * 512 + lane * 4];
        f16x4 v5  = *(const f16x4*)&catfull[(size_t)i1.y * 512 + lane * 4];
        f16x4 v6  = *(const f16x4*)&catfull[(size_t)i1.z * 512 + lane * 4];
        f16x4 v7  = *(const f16x4*)&catfull[(size_t)i1.w * 512 + lane * 4];
        f16x4 v8  = *(const f16x4*)&catfull[(size_t)i2.x * 512 + lane * 4];
        f16x4 v9  = *(const f16x4*)&catfull[(size_t)i2.y * 512 + lane * 4];
        f16x4 v10 = *(const f16x4*)&catfull[(size_t)i2.z * 512 + lane * 4];
        f16x4 v11 = *(const f16x4*)&catfull[(size_t)i2.w * 512 + lane * 4];
        f16x4 v12 = *(const f16x4*)&catfull[(size_t)i3.x * 512 + lane * 4];
        f16x4 v13 = *(const f16x4*)&catfull[(size_t)i3.y * 512 + lane * 4];
        f16x4 v14 = *(const f16x4*)&catfull[(size_t)i3.z * 512 + lane * 4];
        f16x4 v15 = *(const f16x4*)&catfull[(size_t)i3.w * 512 + lane * 4];
        acc0.x += ((float)v0.x + (float)v1.x) + ((float)v2.x + (float)v3.x);
        acc0.y += ((float)v0.y + (float)v1.y) + ((float)v2.y + (float)v3.y);
        acc0.z += ((float)v0.z + (float)v1.z) + ((float)v2.z + (float)v3.z);
        acc0.w += ((float)v0.w + (float)v1.w) + ((float)v2.w + (float)v3.w);
        acc1.x += ((float)v4.x + (float)v5.x) + ((float)v6.x + (float)v7.x);
        acc1.y += ((float)v4.y + (float)v5.y) + ((float)v6.y + (float)v7.y);
        acc1.z += ((float)v4.z + (float)v5.z) + ((float)v6.z + (float)v7.z);
        acc1.w += ((float)v4.w + (float)v5.w) + ((float)v6.w + (float)v7.w);
        acc2.x += ((float)v8.x + (float)v9.x) + ((float)v10.x + (float)v11.x);
        acc2.y += ((float)v8.y + (float)v9.y) + ((float)v10.y + (float)v11.y);
        acc2.z += ((float)v8.z + (float)v9.z) + ((float)v10.z + (float)v11.z);
        acc2.w += ((float)v8.w + (float)v9.w) + ((float)v10.w + (float)v11.w);
        acc3.x += ((float)v12.x + (float)v13.x) + ((float)v14.x + (float)v15.x);
        acc3.y += ((float)v12.y + (float)v13.y) + ((float)v14.y + (float)v15.y);
        acc3.z += ((float)v12.z + (float)v13.z) + ((float)v14.z + (float)v15.z);
        acc3.w += ((float)v12.w + (float)v13.w) + ((float)v14.w + (float)v15.w);
    }
    // ---- 4-wide cleanup
    for (; e + 4 <= degc; e += 4) {
        u16x4 i0 = *(const u16x4*)&bk[e];
        f16x4 v0 = *(const f16x4*)&catfull[(size_t)i0.x * 512 + lane * 4];
        f16x4 v1 = *(const f16x4*)&catfull[(size_t)i0.y * 512 + lane * 4];
        f16x4 v2 = *(const f16x4*)&catfull[(size_t)i0.z * 512 + lane * 4];
        f16x4 v3 = *(const f16x4*)&catfull[(size_t)i0.w * 512 + lane * 4];
        acc0.x += ((float)v0.x + (float)v1.x) + ((float)v2.x + (float)v3.x);
        acc0.y += ((float)v0.y + (float)v1.y) + ((float)v2.y + (float)v3.y);
        acc0.z += ((float)v0.z + (float)v1.z) + ((float)v2.z + (float)v3.z);
        acc0.w += ((float)v0.w + (float)v1.w) + ((float)v2.w + (float)v3.w);
    }
    // ---- scalar tail
    for (; e < degc; ++e) {
        int s = bk[e];
        f16x4 v = *(const f16x4*)&catfull[(size_t)s * 512 + lane * 4];
        acc0.x += (float)v.x; acc0.y += (float)v.y;
        acc0.z += (float)v.z; acc0.w += (float)v.w;
    }

    float4 self = ((const float4*)nf)[(size_t)node * 64 + lane];
    float fd = (float)deg;
    f16x4 o;
    o.x = (_Float16)(fd * self.x - ((acc0.x + acc1.x) + (acc2.x + acc3.x)));
    o.y = (_Float16)(fd * self.y - ((acc0.y + acc1.y) + (acc2.y + acc3.y)));
    o.z = (_Float16)(fd * self.z - ((acc0.z + acc1.z) + (acc2.z + acc3.z)));
    o.w = (_Float16)(fd * self.w - ((acc0.w + acc1.w) + (acc2.w + acc3.w)));
    *(f16x4*)&catfull[(size_t)node * 512 + 256 + lane * 4] = o;
}

// ---------------------------------------------------------------------------
// Pure 2-stage GEMM: out = tanh((catfull @ W1t + b1) @ W2t + b2).
// 512 thr / 8 waves; M-tile 16 (grid 625); wave n-tile 32.
__global__ __launch_bounds__(512, 4) void gemm12(
        const _Float16* __restrict__ catfull,
        const _Float16* __restrict__ W1t, const _Float16* __restrict__ W2t,
        const float* __restrict__ b1, const float* __restrict__ b2,
        float* __restrict__ out, int M) {
    __shared__ _Float16 sA[16 * APAD];     // 16.3 KB
    __shared__ _Float16 hbuf[16 * HPAD];   //  8.3 KB

    int tid = threadIdx.x, lane = tid & 63, wid = tid >> 6;   // wid 0..7
    int m0 = blockIdx.x * 16;
    int wn = wid * 32;
    int fm = lane & 15;
    int q  = lane >> 4;
    int fk = q * 8;

    // ---- stage catfull rows -> sA: 16 rows x 64 b128 groups, 2 passes
    {
        int idx = tid;
#pragma unroll
        for (int p = 0; p < 2; ++p, idx += 512) {
            int row = idx >> 6, g = (idx & 63) * 8;
            int r = m0 + row; if (r >= M) r = M - 1;
            *(uint4*)&sA[row * APAD + g] = *(const uint4*)&catfull[(size_t)r * 512 + g];
        }
    }
    __syncthreads();

    // ---- stage 1: h[16][256] = sA @ W1t + b1 ----
    size_t brow[2];
#pragma unroll
    for (int j = 0; j < 2; ++j) brow[j] = (size_t)(wn + j * 16 + fm) * 512 + fk;

    f16x8 wp[4][2];
#pragma unroll
    for (int s = 0; s < 4; ++s)
#pragma unroll
        for (int j = 0; j < 2; ++j)
            wp[s][j] = *(const f16x8*)&W1t[brow[j] + s * 32];

    f32x4 acc[2] = {};
    f16x8 a_cur = *(const f16x8*)&sA[fm * APAD + fk];
#pragma unroll
    for (int kb = 0; kb < 512; kb += 32) {
        int slot = (kb >> 5) & 3;
        f16x8 a_nxt;
        if (kb + 32 < 512) a_nxt = *(const f16x8*)&sA[fm * APAD + kb + 32 + fk];
        f16x8 w0 = wp[slot][0], w1 = wp[slot][1];
        if (kb + 128 < 512) {
            wp[slot][0] = *(const f16x8*)&W1t[brow[0] + kb + 128];
            wp[slot][1] = *(const f16x8*)&W1t[brow[1] + kb + 128];
        }
        acc[0] = __builtin_amdgcn_mfma_f32_16x16x32_f16(a_cur, w0, acc[0], 0, 0, 0);
        acc[1] = __builtin_amdgcn_mfma_f32_16x16x32_f16(a_cur, w1, acc[1], 0, 0, 0);
        if (kb + 32 < 512) a_cur = a_nxt;
    }

    // epilogue 1: hbuf[row][ncol], row = q*4+r, ncol = wn + j*16 + fm
#pragma unroll
    for (int j = 0; j < 2; ++j) {
        int ncol = wn + j * 16 + fm;
        float bv = b1[ncol];
#pragma unroll
        for (int r = 0; r < 4; ++r)
            hbuf[(q * 4 + r) * HPAD + ncol] = (_Float16)(acc[j][r] + bv);
    }
    __syncthreads();

    // ---- stage 2: out[16][256] = tanh(h @ W2t + b2) ----
    size_t brow2[2];
#pragma unroll
    for (int j = 0; j < 2; ++j) brow2[j] = (size_t)(wn + j * 16 + fm) * 256 + fk;

#pragma unroll
    for (int s = 0; s < 4; ++s)
#pragma unroll
        for (int j = 0; j < 2; ++j)
            wp[s][j] = *(const f16x8*)&W2t[brow2[j] + s * 32];

    f32x4 acc2[2] = {};
    a_cur = *(const f16x8*)&hbuf[fm * HPAD + fk];
#pragma unroll
    for (int kb = 0; kb < 256; kb += 32) {
        int slot = (kb >> 5) & 3;
        f16x8 a_nxt;
        if (kb + 32 < 256) a_nxt = *(const f16x8*)&hbuf[fm * HPAD + kb + 32 + fk];
        f16x8 w0 = wp[slot][0], w1 = wp[slot][1];
        if (kb + 128 < 256) {
            wp[slot][0] = *(const f16x8*)&W2t[brow2[0] + kb + 128];
            wp[slot][1] = *(const f16x8*)&W2t[brow2[1] + kb + 128];
        }
        acc2[0] = __builtin_amdgcn_mfma_f32_16x16x32_f16(a_cur, w0, acc2[0], 0, 0, 0);
        acc2[1] = __builtin_amdgcn_mfma_f32_16x16x32_f16(a_cur, w1, acc2[1], 0, 0, 0);
        if (kb + 32 < 256) a_cur = a_nxt;
    }

    // epilogue 2
#pragma unroll
    for (int j = 0; j < 2; ++j) {
        int ncol = wn + j * 16 + fm;
        float bv = b2[ncol];
#pragma unroll
        for (int r = 0; r < 4; ++r) {
            int row = m0 + q * 4 + r;
            if (row < M) out[(size_t)row * 256 + ncol] = tanhf(acc2[j][r] + bv);
        }
    }
}

// ---------------------------------------------------------------------------
extern "C" void kernel_launch(void* const* d_in, const int* in_sizes, int n_in,
                              void* d_out, int out_size, void* d_ws, size_t ws_size,
                              hipStream_t stream) {
    const float* nf  = (const float*)d_in[0];   // [N, 256] fp32
    const float* W1  = (const float*)d_in[1];   // [512, 256]
    const float* b1  = (const float*)d_in[2];   // [256]
    const float* W2  = (const float*)d_in[3];   // [256, 256]
    const float* b2  = (const float*)d_in[4];   // [256]
    const int* esrc  = (const int*)d_in[5];     // [E]
    const int* edst  = (const int*)d_in[6];     // [E]
    float* out = (float*)d_out;                 // [N, 256] fp32

    int N = in_sizes[0] / H2;
    int E = in_sizes[5];

    char* ws = (char*)d_ws;
    size_t off = 0;
    auto take = [&](size_t bytes) { size_t o = off; off += (bytes + 255) / 256 * 256; return o; };
    int*            cursor  = (int*)(ws + take((size_t)N * 4));
    unsigned short* bucket  = (unsigned short*)(ws + take((size_t)N * MAXDEG * 2));
    _Float16*       catfull = (_Float16*)(ws + take((size_t)N * 512 * 2));
    _Float16*       W1t     = (_Float16*)(ws + take(512 * 256 * 2));
    _Float16*       W2t     = (_Float16*)(ws + take(256 * 256 * 2));

    prep<<<(N + 3) / 4, 256, 0, stream>>>(nf, W1, W2, cursor, catfull, W1t, W2t, N);
    scatter_edges<<<(E + 255) / 256, 256, 0, stream>>>(esrc, edst, cursor, bucket, E);
    gather<<<(N + 3) / 4, 256, 0, stream>>>(nf, cursor, bucket, catfull, N);
    gemm12<<<(N + 15) / 16, 512, 0, stream>>>(catfull, W1t, W2t, b1, b2, out, N);
}